// Round 5
// baseline (85.948 us; speedup 1.0000x reference)
//
#include <hip/hip_runtime.h>

#define LL 64
#define NN 20
#define DTC 0.01f
#define NOISEC 1e-3f
#define LN2C 0.69314718056f
#define LOG2E 1.44269504089f

typedef __attribute__((ext_vector_type(8))) short short8x;
typedef __attribute__((ext_vector_type(4))) float f32x4;
typedef __attribute__((ext_vector_type(4))) int v4i;

// pack two f32 -> bf16x2 in ONE instruction (RNE) -- validated R16.
__device__ __forceinline__ unsigned cvt_pk_bf16(float x, float y) {
    unsigned r;
    asm("v_cvt_pk_bf16_f32 %0, %1, %2" : "=v"(r) : "v"(x), "v"(y));
    return r;
}

// Single-step row_shr:D (D=1..15), bound_ctrl zero-fill, applied to all 4
// dwords of a bf16x8 fragment. Bv[d](nh,qd) = Bv[0](nh-d,qd), 0 for nh<d.
template<int CTRL>
__device__ __forceinline__ short8x dpp_shr(short8x v) {
    v4i p = __builtin_bit_cast(v4i, v);
    v4i q;
    q.x = __builtin_amdgcn_update_dpp(0, p.x, CTRL, 0xf, 0xf, true);
    q.y = __builtin_amdgcn_update_dpp(0, p.y, CTRL, 0xf, 0xf, true);
    q.z = __builtin_amdgcn_update_dpp(0, p.z, CTRL, 0xf, 0xf, true);
    q.w = __builtin_amdgcn_update_dpp(0, p.w, CTRL, 0xf, 0xf, true);
    return __builtin_bit_cast(short8x, q);
}

// R17: software-pipelined A-operands. Model (fits R13-R16): single wave per
// SIMD executes a serial stream; LDS service of the 32 in-step A-reads
// (~400-500cy) sat on the step critical path. Now step n's tail issues the
// 32 A-reads for step n+1 (legal: same-wave in-order DS, fill_g(n+1) writes
// gt before the reads issue), so their service hides under step n's MFMA
// phase and step n+1's DPP/fill_g VALU. Single register buffer (live ranges
// don't overlap across the backedge). Bv0 likewise preloaded (R15).
// E-pairs via v_alignbit_b32 (1 op vs 2-3). exp2/cvt_pk from R16 kept.
// Block-Toeplitz MFMA (validated R8/R9): Qn[32I+i] = sum_d sum_k
// G_d[i][k]*Qsrc[32(I-d)+k], G_d[i][k] = g(32d+i-k), g = DT*q_n reversed,
// zero for negative arg. gt copy kk pos w holds r[w+kk] so every A-read is
// one aligned ds_read_b128; DPP bound_ctrl zeros give the B boundary.
__global__ __launch_bounds__(64, 1) void outage_kernel(
    const float* __restrict__ pathloss,
    const float* __restrict__ powers,
    float* __restrict__ out)
{
    __shared__ __align__(16) unsigned short gt[2][8][544];  // 8 shifted copies, ping-pong
    __shared__ __align__(16) unsigned short Qb[2][1024];    // [0,512)=zeros, [512,1024)=data

    const int lane = threadIdx.x;
    const int c = blockIdx.x, b = c >> 6, l = c & 63;
    const int nh = lane & 15;          // MFMA m / n index
    const int qd = lane >> 4;          // MFMA quad (k-group)

    // ---- inline prep: rowsum + diag of pathloss row l (coalesced) ----
    const float pl = pathloss[l * LL + lane];
    float rs = pl;
    #pragma unroll
    for (int mk = 1; mk < 64; mk <<= 1) rs += __shfl_xor(rs, mk, 64);
    const float dg   = __shfl(pl, l, 64);
    const float dsum = rs - dg;

    // per-lane time constants, tau = 8*lane + u:
    //   P2[u]  = 2^(tau*DT)
    //   P1L[u] = (1 - P2[u]) * log2e   (so exp(-(P2-1)*s) == exp2(P1L*s))
    float P2[8], P1L[8];
    #pragma unroll
    for (int u = 0; u < 8; ++u) {
        float e = __builtin_amdgcn_exp2f((8 * lane + u) * DTC);
        P2[u]  = e;
        P1L[u] = (1.f - e) * LOG2E;
    }

    // zero Q prefixes (1 KiB each) and gt tails [512,544) of both buffers
    *((uint4*)&Qb[0][0] + lane) = uint4{0u, 0u, 0u, 0u};
    *((uint4*)&Qb[1][0] + lane) = uint4{0u, 0u, 0u, 0u};
    {
        const int bb = lane >> 5, w = lane & 31;
        #pragma unroll
        for (int k = 0; k < 8; ++k) gt[bb][k][512 + w] = 0;
    }

    // Q0(tau) = 1 - exp2(P1L*s0), bf16 into Qb[0]
    const float p0 = powers[(b * NN + 0) * LL + l];
    const float s0 = dg * p0 / (p0 * dsum + NOISEC);
    float q7;
    {
        float v[8];
        #pragma unroll
        for (int u = 0; u < 8; ++u) v[u] = 1.f - __builtin_amdgcn_exp2f(P1L[u] * s0);
        q7 = v[7];                                  // lane 63: Q0[511]
        uint4 d4 = { cvt_pk_bf16(v[0], v[1]), cvt_pk_bf16(v[2], v[3]),
                     cvt_pk_bf16(v[4], v[5]), cvt_pk_bf16(v[6], v[7]) };
        *(uint4*)&Qb[0][512 + 8 * lane] = d4;
    }

    const float p1v = powers[(b * NN + 1) * LL + l];
    float lossCh = 1.f + p0 + (p1v + 1.f) * q7;     // only lane 63's is used

    // fill the 8 shifted copies of r[tau] = DT*q_n(tau) for a step into buf
    auto fill_g = [&](int buf, float p) {
        float s  = dg * p / (p * dsum + NOISEC);
        float cm = s * LN2C * DTC;
        unsigned F[8];                               // F[0..3] own pairs, F[4..7] neighbor
        #pragma unroll
        for (int w = 0; w < 4; ++w) {
            float a  = __builtin_amdgcn_exp2f(P1L[2 * w]     * s) * (P2[2 * w]     * cm);
            float bb = __builtin_amdgcn_exp2f(P1L[2 * w + 1] * s) * (P2[2 * w + 1] * cm);
            F[w] = cvt_pk_bf16(a, bb);
        }
        #pragma unroll
        for (int w = 0; w < 4; ++w) {
            unsigned t = (unsigned)__shfl_down((int)F[w], 1, 64);
            F[4 + w] = (lane == 63) ? 0u : t;       // tau >= 512 -> 0
        }
        unsigned E[7];                               // odd-phase pairs: 1 alignbit each
        #pragma unroll
        for (int j = 0; j < 7; ++j) E[j] = __builtin_amdgcn_alignbit(F[j + 1], F[j], 16);
        #pragma unroll
        for (int k = 0; k < 8; ++k) {               // copy k pos 8L+w holds r[8L+w+k]
            uint4 d4;
            if ((k & 1) == 0) d4 = uint4{F[k / 2], F[k / 2 + 1], F[k / 2 + 2], F[k / 2 + 3]};
            else              d4 = uint4{E[k / 2], E[k / 2 + 1], E[k / 2 + 2], E[k / 2 + 3]};
            *(uint4*)&gt[buf][k][8 * lane] = d4;
        }
    };
    fill_g(1, p1v);                                 // g-table for step n=1

    const int kk    = (7 - nh) & 7;                 // this lane's copy index
    const int baseA = 511 - nh + 8 * qd - kk;       // == 0 mod 8 (16B aligned)
    const int baseB = 512 + 32 * nh + 8 * qd;
    const int dstw  = 512 + 32 * nh + 4 * qd;       // +16 for M-tile 1

    float pnext = powers[(b * NN + 2) * LL + l];    // pw[n+1] entering n=1

    // ---- pipeline prologue: B fragment + A operands for step n=1 ----
    // (issued after Q0 store / fill_g(1) writes; same-wave in-order DS)
    short8x Bv0 = *(const short8x*)&Qb[0][baseB];
    short8x A0v[16], A1v[16];
    {
        const unsigned short* pg1 = &gt[1][kk][0];
        #pragma unroll
        for (int d = 0; d < 16; ++d) {
            A0v[d] = *(const short8x*)&pg1[baseA - 32 * d];
            A1v[d] = *(const short8x*)&pg1[baseA - 32 * d - 16];
        }
    }

    for (int n = 1; n < NN; ++n) {
        unsigned short* pdst = &Qb[n & 1][0];

        // issue next-next power load early (lands during this step's work)
        float pfut = 0.f;
        if (n <= NN - 3) pfut = powers[(b * NN + n + 2) * LL + l];

        // ---- B: preloaded Bv0 + 15 INDEPENDENT row_shr:d derivations ----
        short8x Bv[16];
        Bv[0]  = Bv0;
        Bv[1]  = dpp_shr<0x111>(Bv0);
        Bv[2]  = dpp_shr<0x112>(Bv0);
        Bv[3]  = dpp_shr<0x113>(Bv0);
        Bv[4]  = dpp_shr<0x114>(Bv0);
        Bv[5]  = dpp_shr<0x115>(Bv0);
        Bv[6]  = dpp_shr<0x116>(Bv0);
        Bv[7]  = dpp_shr<0x117>(Bv0);
        Bv[8]  = dpp_shr<0x118>(Bv0);
        Bv[9]  = dpp_shr<0x119>(Bv0);
        Bv[10] = dpp_shr<0x11A>(Bv0);
        Bv[11] = dpp_shr<0x11B>(Bv0);
        Bv[12] = dpp_shr<0x11C>(Bv0);
        Bv[13] = dpp_shr<0x11D>(Bv0);
        Bv[14] = dpp_shr<0x11E>(Bv0);
        Bv[15] = dpp_shr<0x11F>(Bv0);

        // ---- fill g-table for step n+1 (independent buffer) ----
        if (n < NN - 1) fill_g((n + 1) & 1, pnext);

        // ---- 4 independent MFMA chains on PREFETCHED A (d even/odd x 2 tiles) ----
        f32x4 acc0a = {0.f, 0.f, 0.f, 0.f}, acc0b = {0.f, 0.f, 0.f, 0.f};
        f32x4 acc1a = {0.f, 0.f, 0.f, 0.f}, acc1b = {0.f, 0.f, 0.f, 0.f};
        #pragma unroll
        for (int d = 0; d < 16; d += 2) {
            acc0a = __builtin_amdgcn_mfma_f32_16x16x32_bf16(A0v[d],     Bv[d],     acc0a, 0, 0, 0);
            acc1a = __builtin_amdgcn_mfma_f32_16x16x32_bf16(A1v[d],     Bv[d],     acc1a, 0, 0, 0);
            acc0b = __builtin_amdgcn_mfma_f32_16x16x32_bf16(A0v[d + 1], Bv[d + 1], acc0b, 0, 0, 0);
            acc1b = __builtin_amdgcn_mfma_f32_16x16x32_bf16(A1v[d + 1], Bv[d + 1], acc1b, 0, 0, 0);
        }
        f32x4 acc0 = acc0a + acc0b;
        f32x4 acc1 = acc1a + acc1b;

        // write Qn (bf16): lane holds rows 4qd..4qd+3 of both M-tiles, col nh
        *(uint2*)&pdst[dstw]      = uint2{cvt_pk_bf16(acc0.x, acc0.y), cvt_pk_bf16(acc0.z, acc0.w)};
        *(uint2*)&pdst[dstw + 16] = uint2{cvt_pk_bf16(acc1.x, acc1.y), cvt_pk_bf16(acc1.z, acc1.w)};

        // ---- pipeline tail: issue step n+1's B + A reads NOW (in-order DS:
        //      they follow the Qn writes and fill_g(n+1) writes, so they see
        //      fresh data; service hides under this step's drain + next
        //      step's DPP/fill_g VALU) ----
        if (n < NN - 1) {
            Bv0 = *(const short8x*)&pdst[baseB];
            const unsigned short* pgn = &gt[(n + 1) & 1][kk][0];
            #pragma unroll
            for (int d = 0; d < 16; ++d) {
                A0v[d] = *(const short8x*)&pgn[baseA - 32 * d];
                A1v[d] = *(const short8x*)&pgn[baseA - 32 * d - 16];
            }
        }

        // loss tap: lane 63 acc1.w == Qn[511] (row 31, col 15), fp32 precision
        float wgt = (n < NN - 1) ? (pnext + 1.f) : 1.f;   // pnext == pw[n+1]
        lossCh += wgt * acc1.w;
        pnext = pfut;
    }

    if (lane == 63) atomicAdd(out, lossCh);
}

extern "C" void kernel_launch(void* const* d_in, const int* in_sizes, int n_in,
                              void* d_out, int out_size, void* d_ws, size_t ws_size,
                              hipStream_t stream) {
    const float* pathloss = (const float*)d_in[0];
    const float* powers   = (const float*)d_in[1];
    float* outp = (float*)d_out;

    (void)hipMemsetAsync(d_out, 0, sizeof(float) * out_size, stream);
    outage_kernel<<<16 * LL, 64, 0, stream>>>(pathloss, powers, outp);
}

// Round 6
// 85.931 us; speedup vs baseline: 1.0002x; 1.0002x over previous
//
#include <hip/hip_runtime.h>

#define LL 64
#define NN 20
#define DTC 0.01f
#define NOISEC 1e-3f
#define LN2C 0.69314718056f
#define LOG2E 1.44269504089f

typedef __attribute__((ext_vector_type(8))) short short8x;
typedef __attribute__((ext_vector_type(4))) float f32x4;

// pack two f32 -> bf16x2 in ONE instruction (RNE) -- validated R16.
__device__ __forceinline__ unsigned cvt_pk_bf16(float x, float y) {
    unsigned r;
    asm("v_cvt_pk_bf16_f32 %0, %1, %2" : "=v"(r) : "v"(x), "v"(y));
    return r;
}

// R18: ALL 16 B-fragments read directly from LDS and prefetched at the loop
// tail (DPP derivation deleted). Ledger: R14 (+VALU) regressed 1:1, R16
// (-VALU) won 1:1, R13/R15/R17 (TLP / latency scheduling) neutral -> the
// kernel is a serial VALU-issue machine; LDS pipe is shared and half-idle.
// The 15 dpp_shr x4 ops (=60 VALU/step) are replaced by 15 ds_read_b128 on
// the prefetch path: Bv[d](nh,qd) = Qsrc[32(nh-d)+8qd+j] = psrc[baseB-32d],
// with the Qb zero-prefix [0,512) supplying the nh-d<0 boundary (this is
// what the prefix was designed for). After this, the step head has NO
// LDS-dependent consumer: every MFMA operand is in registers at loop entry.
// Block-Toeplitz MFMA (validated R8/R9): Qn[32I+i] = sum_d sum_k
// G_d[i][k]*Qsrc[32(I-d)+k], G_d[i][k] = g(32d+i-k), g = DT*q_n reversed,
// zero for negative arg. gt copy kk pos w holds r[w+kk] so every A-read is
// one aligned ds_read_b128. exp2/cvt_pk (R16) and A-prefetch (R17) kept.
__global__ __launch_bounds__(64, 1) void outage_kernel(
    const float* __restrict__ pathloss,
    const float* __restrict__ powers,
    float* __restrict__ out)
{
    __shared__ __align__(16) unsigned short gt[2][8][544];  // 8 shifted copies, ping-pong
    __shared__ __align__(16) unsigned short Qb[2][1024];    // [0,512)=zeros, [512,1024)=data

    const int lane = threadIdx.x;
    const int c = blockIdx.x, b = c >> 6, l = c & 63;
    const int nh = lane & 15;          // MFMA m / n index
    const int qd = lane >> 4;          // MFMA quad (k-group)

    // ---- inline prep: rowsum + diag of pathloss row l (coalesced) ----
    const float pl = pathloss[l * LL + lane];
    float rs = pl;
    #pragma unroll
    for (int mk = 1; mk < 64; mk <<= 1) rs += __shfl_xor(rs, mk, 64);
    const float dg   = __shfl(pl, l, 64);
    const float dsum = rs - dg;

    // per-lane time constants, tau = 8*lane + u:
    //   P2[u]  = 2^(tau*DT)
    //   P1L[u] = (1 - P2[u]) * log2e   (so exp(-(P2-1)*s) == exp2(P1L*s))
    float P2[8], P1L[8];
    #pragma unroll
    for (int u = 0; u < 8; ++u) {
        float e = __builtin_amdgcn_exp2f((8 * lane + u) * DTC);
        P2[u]  = e;
        P1L[u] = (1.f - e) * LOG2E;
    }

    // zero Q prefixes (1 KiB each) and gt tails [512,544) of both buffers
    *((uint4*)&Qb[0][0] + lane) = uint4{0u, 0u, 0u, 0u};
    *((uint4*)&Qb[1][0] + lane) = uint4{0u, 0u, 0u, 0u};
    {
        const int bb = lane >> 5, w = lane & 31;
        #pragma unroll
        for (int k = 0; k < 8; ++k) gt[bb][k][512 + w] = 0;
    }

    // Q0(tau) = 1 - exp2(P1L*s0), bf16 into Qb[0]
    const float p0 = powers[(b * NN + 0) * LL + l];
    const float s0 = dg * p0 / (p0 * dsum + NOISEC);
    float q7;
    {
        float v[8];
        #pragma unroll
        for (int u = 0; u < 8; ++u) v[u] = 1.f - __builtin_amdgcn_exp2f(P1L[u] * s0);
        q7 = v[7];                                  // lane 63: Q0[511]
        uint4 d4 = { cvt_pk_bf16(v[0], v[1]), cvt_pk_bf16(v[2], v[3]),
                     cvt_pk_bf16(v[4], v[5]), cvt_pk_bf16(v[6], v[7]) };
        *(uint4*)&Qb[0][512 + 8 * lane] = d4;
    }

    const float p1v = powers[(b * NN + 1) * LL + l];
    float lossCh = 1.f + p0 + (p1v + 1.f) * q7;     // only lane 63's is used

    // fill the 8 shifted copies of r[tau] = DT*q_n(tau) for a step into buf
    auto fill_g = [&](int buf, float p) {
        float s  = dg * p / (p * dsum + NOISEC);
        float cm = s * LN2C * DTC;
        unsigned F[8];                               // F[0..3] own pairs, F[4..7] neighbor
        #pragma unroll
        for (int w = 0; w < 4; ++w) {
            float a  = __builtin_amdgcn_exp2f(P1L[2 * w]     * s) * (P2[2 * w]     * cm);
            float bb = __builtin_amdgcn_exp2f(P1L[2 * w + 1] * s) * (P2[2 * w + 1] * cm);
            F[w] = cvt_pk_bf16(a, bb);
        }
        #pragma unroll
        for (int w = 0; w < 4; ++w) {
            unsigned t = (unsigned)__shfl_down((int)F[w], 1, 64);
            F[4 + w] = (lane == 63) ? 0u : t;       // tau >= 512 -> 0
        }
        unsigned E[7];                               // odd-phase pairs: 1 alignbit each
        #pragma unroll
        for (int j = 0; j < 7; ++j) E[j] = __builtin_amdgcn_alignbit(F[j + 1], F[j], 16);
        #pragma unroll
        for (int k = 0; k < 8; ++k) {               // copy k pos 8L+w holds r[8L+w+k]
            uint4 d4;
            if ((k & 1) == 0) d4 = uint4{F[k / 2], F[k / 2 + 1], F[k / 2 + 2], F[k / 2 + 3]};
            else              d4 = uint4{E[k / 2], E[k / 2 + 1], E[k / 2 + 2], E[k / 2 + 3]};
            *(uint4*)&gt[buf][k][8 * lane] = d4;
        }
    };
    fill_g(1, p1v);                                 // g-table for step n=1

    const int kk    = (7 - nh) & 7;                 // this lane's copy index
    const int baseA = 511 - nh + 8 * qd - kk;       // == 0 mod 8 (16B aligned)
    const int baseB = 512 + 32 * nh + 8 * qd;       // -32d stays >= 32 (zero prefix)
    const int dstw  = 512 + 32 * nh + 4 * qd;       // +16 for M-tile 1

    float pnext = powers[(b * NN + 2) * LL + l];    // pw[n+1] entering n=1

    // ---- pipeline prologue: ALL operands for step n=1 ----
    // (issued after Q0 store / fill_g(1) writes; same-wave in-order DS)
    short8x Bv[16], A0v[16], A1v[16];
    {
        const unsigned short* pg1 = &gt[1][kk][0];
        #pragma unroll
        for (int d = 0; d < 16; ++d) {
            Bv[d]  = *(const short8x*)&Qb[0][baseB - 32 * d];
            A0v[d] = *(const short8x*)&pg1[baseA - 32 * d];
            A1v[d] = *(const short8x*)&pg1[baseA - 32 * d - 16];
        }
    }

    for (int n = 1; n < NN; ++n) {
        unsigned short* pdst = &Qb[n & 1][0];

        // issue next-next power load early (lands during this step's work)
        float pfut = 0.f;
        if (n <= NN - 3) pfut = powers[(b * NN + n + 2) * LL + l];

        // ---- fill g-table for step n+1 (independent buffer) ----
        if (n < NN - 1) fill_g((n + 1) & 1, pnext);

        // ---- 4 independent MFMA chains, all operands PREFETCHED ----
        f32x4 acc0a = {0.f, 0.f, 0.f, 0.f}, acc0b = {0.f, 0.f, 0.f, 0.f};
        f32x4 acc1a = {0.f, 0.f, 0.f, 0.f}, acc1b = {0.f, 0.f, 0.f, 0.f};
        #pragma unroll
        for (int d = 0; d < 16; d += 2) {
            acc0a = __builtin_amdgcn_mfma_f32_16x16x32_bf16(A0v[d],     Bv[d],     acc0a, 0, 0, 0);
            acc1a = __builtin_amdgcn_mfma_f32_16x16x32_bf16(A1v[d],     Bv[d],     acc1a, 0, 0, 0);
            acc0b = __builtin_amdgcn_mfma_f32_16x16x32_bf16(A0v[d + 1], Bv[d + 1], acc0b, 0, 0, 0);
            acc1b = __builtin_amdgcn_mfma_f32_16x16x32_bf16(A1v[d + 1], Bv[d + 1], acc1b, 0, 0, 0);
        }
        f32x4 acc0 = acc0a + acc0b;
        f32x4 acc1 = acc1a + acc1b;

        // write Qn (bf16): lane holds rows 4qd..4qd+3 of both M-tiles, col nh
        *(uint2*)&pdst[dstw]      = uint2{cvt_pk_bf16(acc0.x, acc0.y), cvt_pk_bf16(acc0.z, acc0.w)};
        *(uint2*)&pdst[dstw + 16] = uint2{cvt_pk_bf16(acc1.x, acc1.y), cvt_pk_bf16(acc1.z, acc1.w)};

        // ---- pipeline tail: issue step n+1's B + A reads NOW (in-order DS:
        //      they follow the Qn writes and fill_g(n+1) writes, so they see
        //      fresh data; service hides under this step's drain + next
        //      step's fill_g VALU + MFMA issue) ----
        if (n < NN - 1) {
            const unsigned short* pgn = &gt[(n + 1) & 1][kk][0];
            #pragma unroll
            for (int d = 0; d < 16; ++d) {
                Bv[d]  = *(const short8x*)&pdst[baseB - 32 * d];
                A0v[d] = *(const short8x*)&pgn[baseA - 32 * d];
                A1v[d] = *(const short8x*)&pgn[baseA - 32 * d - 16];
            }
        }

        // loss tap: lane 63 acc1.w == Qn[511] (row 31, col 15), fp32 precision
        float wgt = (n < NN - 1) ? (pnext + 1.f) : 1.f;   // pnext == pw[n+1]
        lossCh += wgt * acc1.w;
        pnext = pfut;
    }

    if (lane == 63) atomicAdd(out, lossCh);
}

extern "C" void kernel_launch(void* const* d_in, const int* in_sizes, int n_in,
                              void* d_out, int out_size, void* d_ws, size_t ws_size,
                              hipStream_t stream) {
    const float* pathloss = (const float*)d_in[0];
    const float* powers   = (const float*)d_in[1];
    float* outp = (float*)d_out;

    (void)hipMemsetAsync(d_out, 0, sizeof(float) * out_size, stream);
    outage_kernel<<<16 * LL, 64, 0, stream>>>(pathloss, powers, outp);
}